// Round 5
// baseline (1055.657 us; speedup 1.0000x reference)
//
#include <hip/hip_runtime.h>
#include <hip/hip_cooperative_groups.h>

typedef short bfv8 __attribute__((ext_vector_type(8)));  // 8 x bf16 (4 VGPRs)
typedef float fv4  __attribute__((ext_vector_type(4)));  // 4 x f32 accum
typedef unsigned long long u64;

#define T_STEPS 128
#define BATCH   64
#define FDIM    512
#define HDIM    1024
#define NCLS    513
// h ring slot: 65536 elements, BLOCK-MAJOR layout [4 grp][64 blk][16 batch][16 unit]
#define HSLOT   65536

#define PREP_N0 4194304            // convert_x  (T*B*F)
#define PREP_N1 2097152            // expand_x   (NCOL*FDIM)
#define PREP_N2 4194304            // expand_h   (NCOL*HDIM)
#define PREP_N3 4096               // bias
#define PREP_N4 65536              // zero h ring slot 0 (ushorts)
#define PREP_N5 4096               // zero flags (ints)
#define PREP_TOTAL (PREP_N0 + PREP_N1 + PREP_N2 + PREP_N3 + PREP_N4 + PREP_N5)

static __device__ __forceinline__ float b2f(unsigned short u) {
  union { unsigned int i; float f; } v; v.i = ((unsigned int)u) << 16; return v.f;
}
static __device__ __forceinline__ unsigned short f2b(float f) {
  union { float f; unsigned int i; } v; v.f = f;
  unsigned int r = v.i + 0x7FFFu + ((v.i >> 16) & 1u);   // RNE
  return (unsigned short)(r >> 16);
}
static __device__ __forceinline__ float sigm(float x) { return 1.0f / (1.0f + __expf(-x)); }
static __device__ __forceinline__ float tanh_f(float x) {
  float e = __expf(-2.0f * fabsf(x));
  float t = (1.0f - e) / (1.0f + e);
  return x >= 0.0f ? t : -t;
}

// ---- dtype detector: bf16 mode iff even-index ushorts look like bf16 N(0,1) ----
__global__ void detect_k(const unsigned short* __restrict__ xr, int* __restrict__ flag) {
  __shared__ int cnt;
  if (threadIdx.x == 0) cnt = 0;
  __syncthreads();
  int local = 0;
  for (int s = 0; s < 4; ++s) {
    int i = threadIdx.x + 256 * s;
    unsigned short u = xr[2 * i];
    int e = (u >> 7) & 0xFF;
    if (e >= 112 && e <= 131) local++;
  }
  atomicAdd(&cnt, local);
  __syncthreads();
  if (threadIdx.x == 0) *flag = (cnt >= 512) ? 1 : 0;
}

// ---- merged prep: convert x, expand WXT/WHT (tessarine big, transposed,
// gate-interleaved), bias, zero h-ring slot 0 and the flag array.
__global__ void prep_k(const void* __restrict__ x,
                       const void* w0x, const void* w1x, const void* w2x, const void* w3x,
                       const void* w0h, const void* w1h, const void* w2h, const void* w3h,
                       const void* b0, const void* b1, const void* b2, const void* b3,
                       const int* __restrict__ flagp,
                       unsigned short* __restrict__ xbf,
                       unsigned short* __restrict__ WXT,
                       unsigned short* __restrict__ WHT,
                       float* __restrict__ biasI,
                       unsigned short* __restrict__ hring0,
                       int* __restrict__ flags) {
  int fl = *flagp;
  long idx = (long)blockIdx.x * 256 + threadIdx.x;
  if (idx < PREP_N0) {
    int i = (int)idx;
    xbf[i] = fl ? ((const unsigned short*)x)[i] : f2b(((const float*)x)[i]);
    return;
  }
  idx -= PREP_N0;
  if (idx < PREP_N1) {
    int i = (int)idx;
    int n = i >> 9, k = i & 511;
    int j = n >> 2, g = n & 3;
    int rb = k >> 7, p = k & 127;               // FDIM/4 = 128
    int cb = j >> 8, q = j & 255;               // HDIM/4 = 256
    int comp = rb ^ cb;
    int neg = (rb & 1) && !(cb & 1);
    const void* W = (g == 0) ? w0x : (g == 1) ? w1x : (g == 2) ? w2x : w3x;
    int off = comp * (128 * 256) + p * 256 + q;
    unsigned short v;
    if (fl) { v = ((const unsigned short*)W)[off]; if (neg) v ^= 0x8000u; }
    else    { float f = ((const float*)W)[off]; if (neg) f = -f; v = f2b(f); }
    WXT[i] = v;
    return;
  }
  idx -= PREP_N1;
  if (idx < PREP_N2) {
    int i = (int)idx;
    int n = i >> 10, k = i & 1023;
    int j = n >> 2, g = n & 3;
    int rb = k >> 8, p = k & 255;               // HDIM/4 = 256
    int cb = j >> 8, q = j & 255;
    int comp = rb ^ cb;
    int neg = (rb & 1) && !(cb & 1);
    const void* W = (g == 0) ? w0h : (g == 1) ? w1h : (g == 2) ? w2h : w3h;
    int off = comp * (256 * 256) + p * 256 + q;
    unsigned short v;
    if (fl) { v = ((const unsigned short*)W)[off]; if (neg) v ^= 0x8000u; }
    else    { float f = ((const float*)W)[off]; if (neg) f = -f; v = f2b(f); }
    WHT[i] = v;
    return;
  }
  idx -= PREP_N2;
  if (idx < PREP_N3) {
    int i = (int)idx;                           // < 4096
    int j = i >> 2, g = i & 3;
    const void* B = (g == 0) ? b0 : (g == 1) ? b1 : (g == 2) ? b2 : b3;
    biasI[i] = fl ? b2f(((const unsigned short*)B)[j]) : ((const float*)B)[j];
    return;
  }
  idx -= PREP_N3;
  if (idx < PREP_N4) { hring0[(int)idx] = 0; return; }   // h[0] = 0
  idx -= PREP_N4;
  flags[(int)idx] = 0;                                   // barrier flags = 0
}

// ---- tail dot: 512-length partial dot for the fused final linear ----
static __device__ __forceinline__ float dot512_tail(const unsigned short* __restrict__ hfin,
                                                    const void* __restrict__ fw, int fl,
                                                    int b, int col, int half) {
  float s = 0.f;
  int k0 = half * 512;
  if (fl) {
    const unsigned short* fwp = (const unsigned short*)fw;
#pragma unroll 8
    for (int k = k0; k < k0 + 512; ++k)
      s = fmaf(b2f(hfin[((k >> 4) << 8) + b * 16 + (k & 15)]),
               b2f(fwp[k * NCLS + col]), s);
  } else {
    const float* fwp = (const float*)fw;
#pragma unroll 8
    for (int k = k0; k < k0 + 512; ++k)
      s = fmaf(b2f(hfin[((k >> 4) << 8) + b * 16 + (k & 15)]),
               fwp[k * NCLS + col], s);
  }
  return s;
}

// ---- Phase B: 128-step recurrence + fused final linear.
// R15: revert the loop to the EXACT R12 schedule (measured best, 746us):
//   - wave0: Hp-read -> h-store -> vmcnt(0) -> flag -> poll IMMEDIATELY.
//     Its x-GEMM for step t is deferred to the TOP of iteration t, where it
//     runs UNDER the in-flight h-load latency (that's why R12 beat R14: the
//     flag-firer detects earliest and issues the next h-loads earliest).
//   - waves 1-3: x-GEMM for t+1, then poll. No release barrier.
// Kept from R14: fused memsets, fused final-linear tail (flag/poll now run
// at t=127 so final h is agent-visible), 4-chain h-GEMM.
// NEW in R15: flags packed at stride 1 int (64 flags/group = 4 cache lines,
// was 64 lines). The 64-lane poll gather's completion = max of per-line
// latencies; max-of-4 instead of max-of-64 cuts the detect tail. Flag writes
// are plain stores to distinct 4B offsets (byte-enable partial-line writes,
// no RMW -> no R10 same-address serialization).
__global__ void __launch_bounds__(256, 1) phaseB_k(const unsigned short* __restrict__ xbf,
                                                   const unsigned short* __restrict__ WXT,
                                                   const unsigned short* __restrict__ WHT,
                                                   const float* __restrict__ biasI,
                                                   unsigned short* __restrict__ hring,
                                                   int* __restrict__ flags,
                                                   const int* __restrict__ flagp,
                                                   const void* __restrict__ fcw,
                                                   const void* __restrict__ fcb,
                                                   void* __restrict__ out) {
  __shared__ unsigned short Wh[64][1032];     // 64 n-cols x 1024 k (+8 pad): 132 KB
  __shared__ float Pl[4][16][16];             // per-wave transpose staging
  __shared__ __align__(16) unsigned short Hp[16][16];  // block h gather
  __shared__ float Cred[128];                 // tail split-K combine
  int tid = threadIdx.x;
  int fl = *flagp;
  int grp = blockIdx.x >> 6;                  // 0..3 : batch group
  int blk = blockIdx.x & 63;                  // 0..63: N-col block within group
  int n0  = blk * 64;
  for (int c = tid; c < 64 * 128; c += 256) {
    int row = c >> 7, ch = c & 127;
    *(uint4*)&Wh[row][ch * 8] = *(const uint4*)&WHT[(size_t)(n0 + row) * HDIM + ch * 8];
  }
  __syncthreads();
  int w = tid >> 6, lane = tid & 63;
  int col = lane & 15, quad = lane >> 4;
  int gbatch = grp * 16 + col;                // A-frag batch row AND elementwise batch
  const unsigned short* whp = &Wh[w * 16 + col][quad * 8];
  const unsigned short* wxp = WXT + (size_t)(n0 + w * 16 + col) * FDIM + quad * 8;
  float4 bv = *(const float4*)&biasI[n0 + w * 16 + quad * 4];  // lane's unit gate biases
  int* myflag   = flags + grp * 64 + blk;     // packed: 4 lines per group
  int* pollflag = flags + grp * 64 + lane;    // lane-parallel poll target
  // Consumer fragment base (block-major slot layout). Lane (col,quad),
  // fragment f needs units [f*32+quad*8, +8) of batch gbatch:
  //   blk' = 2f + (quad>>1), u16 = (quad&1)*8  ->  element offset f*512 + fbase.
  size_t fbase = (size_t)grp * 16384 + (size_t)(quad >> 1) * 256
               + (size_t)col * 16 + (size_t)(quad & 1) * 8;
  // Producer region: this block's contiguous 256 elements (512B).
  size_t pregion = (size_t)grp * 16384 + (size_t)blk * 256;
  float creg = 0.0f;                          // c state thread-private
  // prologue: gx for t=0 (all waves)
  fv4 gx0 = {0.f, 0.f, 0.f, 0.f}, gx1 = {0.f, 0.f, 0.f, 0.f};
  {
    const unsigned short* xrow = xbf + (size_t)gbatch * FDIM + quad * 8;
#pragma unroll
    for (int k0 = 0; k0 < FDIM; k0 += 64) {
      bfv8 a0 = *(const bfv8*)(xrow + k0);
      bfv8 b0 = *(const bfv8*)(wxp + k0);
      bfv8 a1 = *(const bfv8*)(xrow + k0 + 32);
      bfv8 b1 = *(const bfv8*)(wxp + k0 + 32);
      gx0 = __builtin_amdgcn_mfma_f32_16x16x32_bf16(a0, b0, gx0, 0, 0, 0);
      gx1 = __builtin_amdgcn_mfma_f32_16x16x32_bf16(a1, b1, gx1, 0, 0, 0);
    }
  }
  for (int t = 0; t < T_STEPS; ++t) {
    const unsigned short* hin  = hring + (size_t)t * HSLOT;
    unsigned short*       hout = hring + (size_t)(t + 1) * HSLOT;
    // h A-fragments, plain cached 16B loads (ring slot lines are fresh ->
    // never stale; dispatch-boundary acquire invalidates across reps).
    const uint4* hq = (const uint4*)(hin + fbase);
    uint4 hs[32];
#pragma unroll
    for (int f = 0; f < 32; ++f) hs[f] = hq[f * 64];   // stride 512 elem = 1KB
    if (w == 0 && t > 0) {
      // Wave0's x-GEMM for CURRENT t, deferred from iteration t-1 so the
      // flag could fire early. Executes under the h-load latency above.
      fv4 g0 = {0.f, 0.f, 0.f, 0.f}, g1 = {0.f, 0.f, 0.f, 0.f};
      const unsigned short* xrow = xbf + (size_t)(t * BATCH + gbatch) * FDIM + quad * 8;
#pragma unroll
      for (int k0 = 0; k0 < FDIM; k0 += 64) {
        bfv8 a0v = *(const bfv8*)(xrow + k0);
        bfv8 b0v = *(const bfv8*)(wxp + k0);
        bfv8 a1v = *(const bfv8*)(xrow + k0 + 32);
        bfv8 b1v = *(const bfv8*)(wxp + k0 + 32);
        g0 = __builtin_amdgcn_mfma_f32_16x16x32_bf16(a0v, b0v, g0, 0, 0, 0);
        g1 = __builtin_amdgcn_mfma_f32_16x16x32_bf16(a1v, b1v, g1, 0, 0, 0);
      }
      gx0 = g0; gx1 = g1;
    }
    // h-GEMM: 4 independent accumulator chains, then sum.
    fv4 acc0 = gx0, acc1 = gx1;
    fv4 acc2 = {0.f, 0.f, 0.f, 0.f}, acc3 = {0.f, 0.f, 0.f, 0.f};
#pragma unroll
    for (int f = 0; f < 32; f += 4) {
      union { uint4 q; bfv8 v; } u0, u1, u2, u3;
      u0.q = hs[f];     u1.q = hs[f + 1];
      u2.q = hs[f + 2]; u3.q = hs[f + 3];
      bfv8 b0 = *(const bfv8*)(whp + f * 32);
      bfv8 b1 = *(const bfv8*)(whp + (f + 1) * 32);
      bfv8 b2 = *(const bfv8*)(whp + (f + 2) * 32);
      bfv8 b3 = *(const bfv8*)(whp + (f + 3) * 32);
      acc0 = __builtin_amdgcn_mfma_f32_16x16x32_bf16(u0.v, b0, acc0, 0, 0, 0);
      acc1 = __builtin_amdgcn_mfma_f32_16x16x32_bf16(u1.v, b1, acc1, 0, 0, 0);
      acc2 = __builtin_amdgcn_mfma_f32_16x16x32_bf16(u2.v, b2, acc2, 0, 0, 0);
      acc3 = __builtin_amdgcn_mfma_f32_16x16x32_bf16(u3.v, b3, acc3, 0, 0, 0);
    }
    fv4 acc = (acc0 + acc1) + (acc2 + acc3);
    // Wave-local transpose through LDS (writer wave == reader wave; no barrier).
#pragma unroll
    for (int r = 0; r < 4; ++r) Pl[w][quad * 4 + r][col] = acc[r];  // D: m=quad*4+r, n=col
    asm volatile("" ::: "memory");
    __builtin_amdgcn_s_waitcnt(0);            // ds_writes visible to own wave's ds_read
    asm volatile("" ::: "memory");
    float4 pv = *(const float4*)&Pl[w][col][quad * 4];  // (batch=col, 4 gates of unit quad)
    float fg = sigm(pv.x + bv.x);
    float ig = sigm(pv.y + bv.y);
    float og = sigm(pv.z + bv.z);
    float av = pv.w + bv.w;
    float cn = ig * tanh_f(av) + fg * creg;
    float hn = og * tanh_f(cn);
    creg = cn;
    // Gather the block's 16 batch x 16 units into LDS (batch-major, 2B each).
    Hp[col][w * 4 + quad] = f2b(hn);
    __syncthreads();                          // (A) Hp complete
    // Wave0: one coalesced 512B store (8 full lines), ack, flag — earliest
    // legal fire point; then straight to poll (R12 schedule).
    if (w == 0) {
      u64 pk = ((const u64*)&Hp[0][0])[lane];
      __hip_atomic_store((u64*)(hout + pregion) + lane, pk,
                         __ATOMIC_RELAXED, __HIP_MEMORY_SCOPE_AGENT);
      asm volatile("s_waitcnt vmcnt(0)" ::: "memory");   // h stores at IF$
      if (lane == 0)
        __hip_atomic_store(myflag, t + 1, __ATOMIC_RELAXED, __HIP_MEMORY_SCOPE_AGENT);
    } else if (t + 1 < T_STEPS) {
      // Waves 1-3: x-GEMM for t+1 overlaps the flag-propagation window.
      fv4 g0 = {0.f, 0.f, 0.f, 0.f}, g1 = {0.f, 0.f, 0.f, 0.f};
      const unsigned short* xrow = xbf + (size_t)((t + 1) * BATCH + gbatch) * FDIM + quad * 8;
#pragma unroll
      for (int k0 = 0; k0 < FDIM; k0 += 64) {
        bfv8 a0v = *(const bfv8*)(xrow + k0);
        bfv8 b0v = *(const bfv8*)(wxp + k0);
        bfv8 a1v = *(const bfv8*)(xrow + k0 + 32);
        bfv8 b1v = *(const bfv8*)(wxp + k0 + 32);
        g0 = __builtin_amdgcn_mfma_f32_16x16x32_bf16(a0v, b0v, g0, 0, 0, 0);
        g1 = __builtin_amdgcn_mfma_f32_16x16x32_bf16(a1v, b1v, g1, 0, 0, 0);
      }
      gx0 = g0; gx1 = g1;
    }
    asm volatile("" ::: "memory");
    // ALL waves poll independently (per-lane early-out); no release barrier.
    u64 done = 0;
    for (;;) {
      int v = 0;
      if (!((done >> lane) & 1))
        v = __hip_atomic_load(pollflag, __ATOMIC_RELAXED, __HIP_MEMORY_SCOPE_AGENT);
      done |= __ballot(v >= t + 1);
      if (done == ~0ull) break;
      __builtin_amdgcn_s_sleep(1);
    }
    asm volatile("" ::: "memory");
  }
  // ---- Fused final linear: out = h @ fco_W + fco_b ----
  // poll(128) passed => all of this group's final h is visible at IF$.
  {
    const unsigned short* hfin = hring + (size_t)T_STEPS * HSLOT + (size_t)grp * 16384;
    int b    = tid & 15;          // batch within group
    int cc   = (tid >> 4) & 7;    // col offset within block's 8-col slice
    int half = tid >> 7;          // K half (0: k<512, 1: k>=512)
    int colm = blk * 8 + cc;      // cols 0..511
    float s = dot512_tail(hfin, fcw, fl, b, colm, half);
    if (half) Cred[tid & 127] = s;
    __syncthreads();
    if (!half) {
      float r = s + Cred[tid];
      float bias = fl ? b2f(((const unsigned short*)fcb)[colm])
                      : ((const float*)fcb)[colm];
      r += bias;
      int oidx = (grp * 16 + b) * NCLS + colm;
      if (fl) ((unsigned short*)out)[oidx] = f2b(r);
      else    ((float*)out)[oidx] = r;
    }
    if (blk == 63) {              // the 513th class column
      float s2 = 0.f;
      if (tid < 32) s2 = dot512_tail(hfin, fcw, fl, tid & 15, 512, tid >> 4);
      __syncthreads();
      if (tid < 32 && (tid >> 4)) Cred[tid & 15] = s2;
      __syncthreads();
      if (tid < 16) {
        float r = s2 + Cred[tid];
        r += fl ? b2f(((const unsigned short*)fcb)[512]) : ((const float*)fcb)[512];
        int oidx = (grp * 16 + tid) * NCLS + 512;
        if (fl) ((unsigned short*)out)[oidx] = f2b(r);
        else    ((float*)out)[oidx] = r;
      }
    }
  }
}

extern "C" void kernel_launch(void* const* d_in, const int* in_sizes, int n_in,
                              void* d_out, int out_size, void* d_ws, size_t ws_size,
                              hipStream_t stream) {
  const void* x   = d_in[0];
  const void* wfx = d_in[1];  const void* bfv = d_in[2];  const void* wfh = d_in[3];
  const void* wix = d_in[4];  const void* biv = d_in[5];  const void* wih = d_in[6];
  const void* wox = d_in[7];  const void* bov = d_in[8];  const void* woh = d_in[9];
  const void* wcx = d_in[10]; const void* bcv = d_in[11]; const void* wch = d_in[12];
  const void* fcw = d_in[13]; const void* fcb = d_in[14];

  char* ws = (char*)d_ws;
  int*            flag  = (int*)           (ws);                 // 256 B
  unsigned short* WXT   = (unsigned short*)(ws + 256);           // 4 MB
  unsigned short* WHT   = (unsigned short*)(ws + 4194560);       // 8 MB
  float*          biasI = (float*)         (ws + 12583168);      // 16 KB
  unsigned short* xbf   = (unsigned short*)(ws + 12599552);      // 8 MB
  unsigned short* hring = (unsigned short*)(ws + 20988160);      // 129 x 128 KB = 16.9 MB
  int*            flags = (int*)           (ws + 37896448);      // 16 KB -> total ~37.9 MB

  detect_k<<<1, 256, 0, stream>>>((const unsigned short*)x, flag);
  prep_k<<<PREP_TOTAL / 256, 256, 0, stream>>>(x, wfx, wix, wox, wcx,
                                               wfh, wih, woh, wch,
                                               bfv, biv, bov, bcv,
                                               flag, xbf, WXT, WHT, biasI,
                                               hring, flags);

  const unsigned short* p_x = xbf;
  const unsigned short* p_wx = WXT;
  const unsigned short* p_wh = WHT;
  const float* p_bi = biasI;
  unsigned short* p_hr = hring;
  int* p_fl = flags;
  const int* p_flag = flag;
  const void* p_fcw = fcw;
  const void* p_fcb = fcb;
  void* p_out = d_out;
  void* kargs[] = { (void*)&p_x, (void*)&p_wx, (void*)&p_wh, (void*)&p_bi,
                    (void*)&p_hr, (void*)&p_fl, (void*)&p_flag,
                    (void*)&p_fcw, (void*)&p_fcb, (void*)&p_out };
  hipLaunchCooperativeKernel((void*)phaseB_k, dim3(256), dim3(256), kargs, 0, stream);
}

// Round 6
// 968.036 us; speedup vs baseline: 1.0905x; 1.0905x over previous
//
#include <hip/hip_runtime.h>
#include <hip/hip_cooperative_groups.h>

typedef short bfv8 __attribute__((ext_vector_type(8)));  // 8 x bf16 (4 VGPRs)
typedef float fv4  __attribute__((ext_vector_type(4)));  // 4 x f32 accum
typedef unsigned long long u64;

#define T_STEPS 128
#define BATCH   64
#define FDIM    512
#define HDIM    1024
#define NCLS    513
// h ring slot: 65536 elements, BLOCK-MAJOR layout [4 grp][64 blk][16 batch][16 unit]
#define HSLOT   65536

#define PREP_N0 4194304            // convert_x  (T*B*F)
#define PREP_N1 2097152            // expand_x   (NCOL*FDIM)
#define PREP_N2 4194304            // expand_h   (NCOL*HDIM)
#define PREP_N3 4096               // bias
#define PREP_N4 65536              // zero h ring slot 0 (ushorts)
#define PREP_N5 4096               // zero flags (ints)
#define PREP_TOTAL (PREP_N0 + PREP_N1 + PREP_N2 + PREP_N3 + PREP_N4 + PREP_N5)

static __device__ __forceinline__ float b2f(unsigned short u) {
  union { unsigned int i; float f; } v; v.i = ((unsigned int)u) << 16; return v.f;
}
static __device__ __forceinline__ unsigned short f2b(float f) {
  union { float f; unsigned int i; } v; v.f = f;
  unsigned int r = v.i + 0x7FFFu + ((v.i >> 16) & 1u);   // RNE
  return (unsigned short)(r >> 16);
}
static __device__ __forceinline__ float sigm(float x) { return 1.0f / (1.0f + __expf(-x)); }
static __device__ __forceinline__ float tanh_f(float x) {
  float e = __expf(-2.0f * fabsf(x));
  float t = (1.0f - e) / (1.0f + e);
  return x >= 0.0f ? t : -t;
}

// ---- dtype detector: bf16 mode iff even-index ushorts look like bf16 N(0,1) ----
__global__ void detect_k(const unsigned short* __restrict__ xr, int* __restrict__ flag) {
  __shared__ int cnt;
  if (threadIdx.x == 0) cnt = 0;
  __syncthreads();
  int local = 0;
  for (int s = 0; s < 4; ++s) {
    int i = threadIdx.x + 256 * s;
    unsigned short u = xr[2 * i];
    int e = (u >> 7) & 0xFF;
    if (e >= 112 && e <= 131) local++;
  }
  atomicAdd(&cnt, local);
  __syncthreads();
  if (threadIdx.x == 0) *flag = (cnt >= 512) ? 1 : 0;
}

// ---- merged prep: convert x, expand WXT/WHT (tessarine big, transposed,
// gate-interleaved), bias, zero h-ring slot 0 and the flag array.
__global__ void prep_k(const void* __restrict__ x,
                       const void* w0x, const void* w1x, const void* w2x, const void* w3x,
                       const void* w0h, const void* w1h, const void* w2h, const void* w3h,
                       const void* b0, const void* b1, const void* b2, const void* b3,
                       const int* __restrict__ flagp,
                       unsigned short* __restrict__ xbf,
                       unsigned short* __restrict__ WXT,
                       unsigned short* __restrict__ WHT,
                       float* __restrict__ biasI,
                       unsigned short* __restrict__ hring0,
                       int* __restrict__ flags) {
  int fl = *flagp;
  long idx = (long)blockIdx.x * 256 + threadIdx.x;
  if (idx < PREP_N0) {
    int i = (int)idx;
    xbf[i] = fl ? ((const unsigned short*)x)[i] : f2b(((const float*)x)[i]);
    return;
  }
  idx -= PREP_N0;
  if (idx < PREP_N1) {
    int i = (int)idx;
    int n = i >> 9, k = i & 511;
    int j = n >> 2, g = n & 3;
    int rb = k >> 7, p = k & 127;               // FDIM/4 = 128
    int cb = j >> 8, q = j & 255;               // HDIM/4 = 256
    int comp = rb ^ cb;
    int neg = (rb & 1) && !(cb & 1);
    const void* W = (g == 0) ? w0x : (g == 1) ? w1x : (g == 2) ? w2x : w3x;
    int off = comp * (128 * 256) + p * 256 + q;
    unsigned short v;
    if (fl) { v = ((const unsigned short*)W)[off]; if (neg) v ^= 0x8000u; }
    else    { float f = ((const float*)W)[off]; if (neg) f = -f; v = f2b(f); }
    WXT[i] = v;
    return;
  }
  idx -= PREP_N1;
  if (idx < PREP_N2) {
    int i = (int)idx;
    int n = i >> 10, k = i & 1023;
    int j = n >> 2, g = n & 3;
    int rb = k >> 8, p = k & 255;               // HDIM/4 = 256
    int cb = j >> 8, q = j & 255;
    int comp = rb ^ cb;
    int neg = (rb & 1) && !(cb & 1);
    const void* W = (g == 0) ? w0h : (g == 1) ? w1h : (g == 2) ? w2h : w3h;
    int off = comp * (256 * 256) + p * 256 + q;
    unsigned short v;
    if (fl) { v = ((const unsigned short*)W)[off]; if (neg) v ^= 0x8000u; }
    else    { float f = ((const float*)W)[off]; if (neg) f = -f; v = f2b(f); }
    WHT[i] = v;
    return;
  }
  idx -= PREP_N2;
  if (idx < PREP_N3) {
    int i = (int)idx;                           // < 4096
    int j = i >> 2, g = i & 3;
    const void* B = (g == 0) ? b0 : (g == 1) ? b1 : (g == 2) ? b2 : b3;
    biasI[i] = fl ? b2f(((const unsigned short*)B)[j]) : ((const float*)B)[j];
    return;
  }
  idx -= PREP_N3;
  if (idx < PREP_N4) { hring0[(int)idx] = 0; return; }   // h[0] = 0
  idx -= PREP_N4;
  flags[(int)idx] = 0;                                   // barrier flags = 0
}

// ---- tail dot: 512-length partial dot for the fused final linear ----
static __device__ __forceinline__ float dot512_tail(const unsigned short* __restrict__ hfin,
                                                    const void* __restrict__ fw, int fl,
                                                    int b, int col, int half) {
  float s = 0.f;
  int k0 = half * 512;
  if (fl) {
    const unsigned short* fwp = (const unsigned short*)fw;
#pragma unroll 8
    for (int k = k0; k < k0 + 512; ++k)
      s = fmaf(b2f(hfin[((k >> 4) << 8) + b * 16 + (k & 15)]),
               b2f(fwp[k * NCLS + col]), s);
  } else {
    const float* fwp = (const float*)fw;
#pragma unroll 8
    for (int k = k0; k < k0 + 512; ++k)
      s = fmaf(b2f(hfin[((k >> 4) << 8) + b * 16 + (k & 15)]),
               fwp[k * NCLS + col], s);
  }
  return s;
}

// ---- Phase B: 128-step recurrence + fused final linear.
// R16: loop is BYTE-FAITHFUL R12 (measured best, 746us/step-loop):
//   - stride-16 flags: ONE inter-XCD writer per cache line. (R15's packed
//     flags put 16 XCD-writers on one line -> partial-line writes serialize
//     at the coherence point -> ~+1.2us/step. Same law as R11's h-store fix.)
//   - 2-chain accumulator (R12 exact; 4-chain never isolated as a win).
//   - wave0: store -> vmcnt(0) -> flag -> poll; its x-GEMM deferred to next
//     iteration top (runs under the 32 in-flight h-loads). waves 1-3:
//     x-GEMM(t+1) -> poll. No barriers.
// Fusions kept (proven cheap): memsets in prep_k; final linear as a tail
// AFTER the loop, enabled by appending one extra sync round (flag=128,
// poll(128)) — the R12 loop itself is untouched.
__global__ void __launch_bounds__(256, 1) phaseB_k(const unsigned short* __restrict__ xbf,
                                                   const unsigned short* __restrict__ WXT,
                                                   const unsigned short* __restrict__ WHT,
                                                   const float* __restrict__ biasI,
                                                   unsigned short* __restrict__ hring,
                                                   int* __restrict__ flags,
                                                   const int* __restrict__ flagp,
                                                   const void* __restrict__ fcw,
                                                   const void* __restrict__ fcb,
                                                   void* __restrict__ out) {
  __shared__ unsigned short Wh[64][1032];     // 64 n-cols x 1024 k (+8 pad): 132 KB
  __shared__ float Pl[4][16][16];             // per-wave transpose staging
  __shared__ __align__(16) unsigned short Hp[16][16];  // block h gather
  __shared__ float Cred[128];                 // tail split-K combine
  int tid = threadIdx.x;
  int fl = *flagp;
  int grp = blockIdx.x >> 6;                  // 0..3 : batch group
  int blk = blockIdx.x & 63;                  // 0..63: N-col block within group
  int n0  = blk * 64;
  for (int c = tid; c < 64 * 128; c += 256) {
    int row = c >> 7, ch = c & 127;
    *(uint4*)&Wh[row][ch * 8] = *(const uint4*)&WHT[(size_t)(n0 + row) * HDIM + ch * 8];
  }
  __syncthreads();
  int w = tid >> 6, lane = tid & 63;
  int col = lane & 15, quad = lane >> 4;
  int gbatch = grp * 16 + col;                // A-frag batch row AND elementwise batch
  const unsigned short* whp = &Wh[w * 16 + col][quad * 8];
  const unsigned short* wxp = WXT + (size_t)(n0 + w * 16 + col) * FDIM + quad * 8;
  float4 bv = *(const float4*)&biasI[n0 + w * 16 + quad * 4];  // lane's unit gate biases
  int* myflag   = flags + (grp * 64 + blk) * 16;   // this block's flag (64 B stride)
  int* pollflag = flags + (grp * 64 + lane) * 16;  // lane-parallel poll target
  // Consumer fragment base (block-major slot layout). Lane (col,quad),
  // fragment f needs units [f*32+quad*8, +8) of batch gbatch:
  //   blk' = 2f + (quad>>1), u16 = (quad&1)*8  ->  element offset f*512 + fbase.
  size_t fbase = (size_t)grp * 16384 + (size_t)(quad >> 1) * 256
               + (size_t)col * 16 + (size_t)(quad & 1) * 8;
  // Producer region: this block's contiguous 256 elements (512B).
  size_t pregion = (size_t)grp * 16384 + (size_t)blk * 256;
  float creg = 0.0f;                          // c state thread-private
  // prologue: gx for t=0 (all waves)
  fv4 gx0 = {0.f, 0.f, 0.f, 0.f}, gx1 = {0.f, 0.f, 0.f, 0.f};
  {
    const unsigned short* xrow = xbf + (size_t)gbatch * FDIM + quad * 8;
#pragma unroll
    for (int k0 = 0; k0 < FDIM; k0 += 64) {
      bfv8 a0 = *(const bfv8*)(xrow + k0);
      bfv8 b0 = *(const bfv8*)(wxp + k0);
      bfv8 a1 = *(const bfv8*)(xrow + k0 + 32);
      bfv8 b1 = *(const bfv8*)(wxp + k0 + 32);
      gx0 = __builtin_amdgcn_mfma_f32_16x16x32_bf16(a0, b0, gx0, 0, 0, 0);
      gx1 = __builtin_amdgcn_mfma_f32_16x16x32_bf16(a1, b1, gx1, 0, 0, 0);
    }
  }
  for (int t = 0; t < T_STEPS; ++t) {
    const unsigned short* hin  = hring + (size_t)t * HSLOT;
    unsigned short*       hout = hring + (size_t)(t + 1) * HSLOT;
    // h A-fragments, plain cached 16B loads (ring slot lines are fresh ->
    // never stale; dispatch-boundary acquire invalidates across reps).
    const uint4* hq = (const uint4*)(hin + fbase);
    uint4 hs[32];
#pragma unroll
    for (int f = 0; f < 32; ++f) hs[f] = hq[f * 64];   // stride 512 elem = 1KB
    if (w == 0 && t > 0) {
      // Wave0's x-GEMM for CURRENT t, deferred from iteration t-1 so the
      // flag could fire early. Executes under the h-load latency above.
      fv4 g0 = {0.f, 0.f, 0.f, 0.f}, g1 = {0.f, 0.f, 0.f, 0.f};
      const unsigned short* xrow = xbf + (size_t)(t * BATCH + gbatch) * FDIM + quad * 8;
#pragma unroll
      for (int k0 = 0; k0 < FDIM; k0 += 64) {
        bfv8 a0v = *(const bfv8*)(xrow + k0);
        bfv8 b0v = *(const bfv8*)(wxp + k0);
        bfv8 a1v = *(const bfv8*)(xrow + k0 + 32);
        bfv8 b1v = *(const bfv8*)(wxp + k0 + 32);
        g0 = __builtin_amdgcn_mfma_f32_16x16x32_bf16(a0v, b0v, g0, 0, 0, 0);
        g1 = __builtin_amdgcn_mfma_f32_16x16x32_bf16(a1v, b1v, g1, 0, 0, 0);
      }
      gx0 = g0; gx1 = g1;
    }
    fv4 acc0 = gx0, acc1 = gx1;               // start from x-GEMM result
#pragma unroll
    for (int f = 0; f < 32; f += 2) {
      union { uint4 q; bfv8 v; } ua, ub;
      ua.q = hs[f];
      ub.q = hs[f + 1];
      bfv8 b0 = *(const bfv8*)(whp + f * 32);
      bfv8 b1 = *(const bfv8*)(whp + (f + 1) * 32);
      acc0 = __builtin_amdgcn_mfma_f32_16x16x32_bf16(ua.v, b0, acc0, 0, 0, 0);
      acc1 = __builtin_amdgcn_mfma_f32_16x16x32_bf16(ub.v, b1, acc1, 0, 0, 0);
    }
    fv4 acc = acc0 + acc1;
    // Wave-local transpose through LDS (writer wave == reader wave; no barrier).
#pragma unroll
    for (int r = 0; r < 4; ++r) Pl[w][quad * 4 + r][col] = acc[r];  // D: m=quad*4+r, n=col
    asm volatile("" ::: "memory");
    __builtin_amdgcn_s_waitcnt(0);            // ds_writes visible to own wave's ds_read
    asm volatile("" ::: "memory");
    float4 pv = *(const float4*)&Pl[w][col][quad * 4];  // (batch=col, 4 gates of unit quad)
    float fg = sigm(pv.x + bv.x);
    float ig = sigm(pv.y + bv.y);
    float og = sigm(pv.z + bv.z);
    float av = pv.w + bv.w;
    float cn = ig * tanh_f(av) + fg * creg;
    float hn = og * tanh_f(cn);
    creg = cn;
    // Gather the block's 16 batch x 16 units into LDS (batch-major, 2B each).
    Hp[col][w * 4 + quad] = f2b(hn);
    __syncthreads();                          // (A) Hp complete
    // Wave0: single coalesced store of the whole 512B region (8 full lines),
    // then ack + flag IMMEDIATELY (earliest legal point).
    if (w == 0) {
      u64 pk = ((const u64*)&Hp[0][0])[lane];
      __hip_atomic_store((u64*)(hout + pregion) + lane, pk,
                         __ATOMIC_RELAXED, __HIP_MEMORY_SCOPE_AGENT);
    }
    if (t + 1 < T_STEPS) {
      if (w == 0) {
        asm volatile("s_waitcnt vmcnt(0)" ::: "memory");   // h stores at IF$
        if (lane == 0)
          __hip_atomic_store(myflag, t + 1, __ATOMIC_RELAXED, __HIP_MEMORY_SCOPE_AGENT);
      } else {
        // Waves 1-3: x-GEMM for t+1 overlaps the flag-propagation window.
        fv4 g0 = {0.f, 0.f, 0.f, 0.f}, g1 = {0.f, 0.f, 0.f, 0.f};
        const unsigned short* xrow = xbf + (size_t)((t + 1) * BATCH + gbatch) * FDIM + quad * 8;
#pragma unroll
        for (int k0 = 0; k0 < FDIM; k0 += 64) {
          bfv8 a0v = *(const bfv8*)(xrow + k0);
          bfv8 b0v = *(const bfv8*)(wxp + k0);
          bfv8 a1v = *(const bfv8*)(xrow + k0 + 32);
          bfv8 b1v = *(const bfv8*)(wxp + k0 + 32);
          g0 = __builtin_amdgcn_mfma_f32_16x16x32_bf16(a0v, b0v, g0, 0, 0, 0);
          g1 = __builtin_amdgcn_mfma_f32_16x16x32_bf16(a1v, b1v, g1, 0, 0, 0);
        }
        gx0 = g0; gx1 = g1;
      }
      asm volatile("" ::: "memory");
      // ALL waves poll independently (per-lane early-out); no release barrier.
      u64 done = 0;
      for (;;) {
        int v = 0;
        if (!((done >> lane) & 1))
          v = __hip_atomic_load(pollflag, __ATOMIC_RELAXED, __HIP_MEMORY_SCOPE_AGENT);
        done |= __ballot(v >= t + 1);
        if (done == ~0ull) break;
        __builtin_amdgcn_s_sleep(1);
      }
      asm volatile("" ::: "memory");
    }
  }
  // ---- Appended final sync round (t=128): make final h agent-visible ----
  if (w == 0) {
    asm volatile("s_waitcnt vmcnt(0)" ::: "memory");       // t=127 h stores acked
    if (lane == 0)
      __hip_atomic_store(myflag, T_STEPS, __ATOMIC_RELAXED, __HIP_MEMORY_SCOPE_AGENT);
  }
  {
    u64 done = 0;
    for (;;) {
      int v = 0;
      if (!((done >> lane) & 1))
        v = __hip_atomic_load(pollflag, __ATOMIC_RELAXED, __HIP_MEMORY_SCOPE_AGENT);
      done |= __ballot(v >= T_STEPS);
      if (done == ~0ull) break;
      __builtin_amdgcn_s_sleep(1);
    }
  }
  asm volatile("" ::: "memory");
  // ---- Fused final linear: out = h @ fco_W + fco_b ----
  {
    const unsigned short* hfin = hring + (size_t)T_STEPS * HSLOT + (size_t)grp * 16384;
    int b    = tid & 15;          // batch within group
    int cc   = (tid >> 4) & 7;    // col offset within block's 8-col slice
    int half = tid >> 7;          // K half (0: k<512, 1: k>=512)
    int colm = blk * 8 + cc;      // cols 0..511
    float s = dot512_tail(hfin, fcw, fl, b, colm, half);
    if (half) Cred[tid & 127] = s;
    __syncthreads();
    if (!half) {
      float r = s + Cred[tid];
      float bias = fl ? b2f(((const unsigned short*)fcb)[colm])
                      : ((const float*)fcb)[colm];
      r += bias;
      int oidx = (grp * 16 + b) * NCLS + colm;
      if (fl) ((unsigned short*)out)[oidx] = f2b(r);
      else    ((float*)out)[oidx] = r;
    }
    if (blk == 63) {              // the 513th class column
      float s2 = 0.f;
      if (tid < 32) s2 = dot512_tail(hfin, fcw, fl, tid & 15, 512, tid >> 4);
      __syncthreads();
      if (tid < 32 && (tid >> 4)) Cred[tid & 15] = s2;
      __syncthreads();
      if (tid < 16) {
        float r = s2 + Cred[tid];
        r += fl ? b2f(((const unsigned short*)fcb)[512]) : ((const float*)fcb)[512];
        int oidx = (grp * 16 + tid) * NCLS + 512;
        if (fl) ((unsigned short*)out)[oidx] = f2b(r);
        else    ((float*)out)[oidx] = r;
      }
    }
  }
}

extern "C" void kernel_launch(void* const* d_in, const int* in_sizes, int n_in,
                              void* d_out, int out_size, void* d_ws, size_t ws_size,
                              hipStream_t stream) {
  const void* x   = d_in[0];
  const void* wfx = d_in[1];  const void* bfv = d_in[2];  const void* wfh = d_in[3];
  const void* wix = d_in[4];  const void* biv = d_in[5];  const void* wih = d_in[6];
  const void* wox = d_in[7];  const void* bov = d_in[8];  const void* woh = d_in[9];
  const void* wcx = d_in[10]; const void* bcv = d_in[11]; const void* wch = d_in[12];
  const void* fcw = d_in[13]; const void* fcb = d_in[14];

  char* ws = (char*)d_ws;
  int*            flag  = (int*)           (ws);                 // 256 B
  unsigned short* WXT   = (unsigned short*)(ws + 256);           // 4 MB
  unsigned short* WHT   = (unsigned short*)(ws + 4194560);       // 8 MB
  float*          biasI = (float*)         (ws + 12583168);      // 16 KB
  unsigned short* xbf   = (unsigned short*)(ws + 12599552);      // 8 MB
  unsigned short* hring = (unsigned short*)(ws + 20988160);      // 129 x 128 KB = 16.9 MB
  int*            flags = (int*)           (ws + 37896448);      // 16 KB -> total ~37.9 MB

  detect_k<<<1, 256, 0, stream>>>((const unsigned short*)x, flag);
  prep_k<<<PREP_TOTAL / 256, 256, 0, stream>>>(x, wfx, wix, wox, wcx,
                                               wfh, wih, woh, wch,
                                               bfv, biv, bov, bcv,
                                               flag, xbf, WXT, WHT, biasI,
                                               hring, flags);

  const unsigned short* p_x = xbf;
  const unsigned short* p_wx = WXT;
  const unsigned short* p_wh = WHT;
  const float* p_bi = biasI;
  unsigned short* p_hr = hring;
  int* p_fl = flags;
  const int* p_flag = flag;
  const void* p_fcw = fcw;
  const void* p_fcb = fcb;
  void* p_out = d_out;
  void* kargs[] = { (void*)&p_x, (void*)&p_wx, (void*)&p_wh, (void*)&p_bi,
                    (void*)&p_hr, (void*)&p_fl, (void*)&p_flag,
                    (void*)&p_fcw, (void*)&p_fcb, (void*)&p_out };
  hipLaunchCooperativeKernel((void*)phaseB_k, dim3(256), dim3(256), kargs, 0, stream);
}

// Round 7
// 883.462 us; speedup vs baseline: 1.1949x; 1.0957x over previous
//
#include <hip/hip_runtime.h>
#include <hip/hip_cooperative_groups.h>

typedef short bfv8 __attribute__((ext_vector_type(8)));  // 8 x bf16 (4 VGPRs)
typedef float fv4  __attribute__((ext_vector_type(4)));  // 4 x f32 accum
typedef unsigned long long u64;

#define T_STEPS 128
#define BATCH   64
#define FDIM    512
#define HDIM    1024
#define NCLS    513
// h ring slot: 65536 elements, BLOCK-MAJOR layout [4 grp][64 blk][16 batch][16 unit]
#define HSLOT   65536

#define PREP_N0V 524288            // convert_x, 8-wide  (T*B*F/8)
#define PREP_N1  2097152           // expand_x   (NCOL*FDIM)
#define PREP_N2  4194304           // expand_h   (NCOL*HDIM)
#define PREP_N3  4096              // bias
#define PREP_N4V 8192              // zero h ring slot 0, 8-wide (65536/8)
#define PREP_N5  4096              // zero flags (ints)
#define PREP_N6  525312            // fcwT transpose (NCLS*HDIM)
#define PREP_TOTAL (PREP_N0V + PREP_N1 + PREP_N2 + PREP_N3 + PREP_N4V + PREP_N5 + PREP_N6)

static __device__ __forceinline__ float b2f(unsigned short u) {
  union { unsigned int i; float f; } v; v.i = ((unsigned int)u) << 16; return v.f;
}
static __device__ __forceinline__ unsigned short f2b(float f) {
  union { float f; unsigned int i; } v; v.f = f;
  unsigned int r = v.i + 0x7FFFu + ((v.i >> 16) & 1u);   // RNE
  return (unsigned short)(r >> 16);
}
static __device__ __forceinline__ float sigm(float x) { return 1.0f / (1.0f + __expf(-x)); }
static __device__ __forceinline__ float tanh_f(float x) {
  float e = __expf(-2.0f * fabsf(x));
  float t = (1.0f - e) / (1.0f + e);
  return x >= 0.0f ? t : -t;
}

// ---- dtype detector: bf16 mode iff even-index ushorts look like bf16 N(0,1) ----
__global__ void detect_k(const unsigned short* __restrict__ xr, int* __restrict__ flag) {
  __shared__ int cnt;
  if (threadIdx.x == 0) cnt = 0;
  __syncthreads();
  int local = 0;
  for (int s = 0; s < 4; ++s) {
    int i = threadIdx.x + 256 * s;
    unsigned short u = xr[2 * i];
    int e = (u >> 7) & 0xFF;
    if (e >= 112 && e <= 131) local++;
  }
  atomicAdd(&cnt, local);
  __syncthreads();
  if (threadIdx.x == 0) *flag = (cnt >= 512) ? 1 : 0;
}

// ---- merged prep: convert x (8-wide), expand WXT/WHT (tessarine big,
// transposed, gate-interleaved), bias, zero hring slot0 + flags, and
// (R17) build fcwT[col][k] in f32 — contiguous-k so the fused tail reads
// float4 streams instead of 2052B-strided scalar line-misses.
__global__ void prep_k(const void* __restrict__ x,
                       const void* w0x, const void* w1x, const void* w2x, const void* w3x,
                       const void* w0h, const void* w1h, const void* w2h, const void* w3h,
                       const void* b0, const void* b1, const void* b2, const void* b3,
                       const void* __restrict__ fcw,
                       const int* __restrict__ flagp,
                       unsigned short* __restrict__ xbf,
                       unsigned short* __restrict__ WXT,
                       unsigned short* __restrict__ WHT,
                       float* __restrict__ biasI,
                       unsigned short* __restrict__ hring0,
                       int* __restrict__ flags,
                       float* __restrict__ fcwT) {
  int fl = *flagp;
  long idx = (long)blockIdx.x * 256 + threadIdx.x;
  if (idx < PREP_N0V) {
    int i = (int)idx * 8;
    if (fl) {
      *(uint4*)&xbf[i] = *(const uint4*)&((const unsigned short*)x)[i];
    } else {
      const float* xf = (const float*)x;
      union { unsigned short s[8]; uint4 q; } o;
#pragma unroll
      for (int e = 0; e < 8; ++e) o.s[e] = f2b(xf[i + e]);
      *(uint4*)&xbf[i] = o.q;
    }
    return;
  }
  idx -= PREP_N0V;
  if (idx < PREP_N1) {
    int i = (int)idx;
    int n = i >> 9, k = i & 511;
    int j = n >> 2, g = n & 3;
    int rb = k >> 7, p = k & 127;               // FDIM/4 = 128
    int cb = j >> 8, q = j & 255;               // HDIM/4 = 256
    int comp = rb ^ cb;
    int neg = (rb & 1) && !(cb & 1);
    const void* W = (g == 0) ? w0x : (g == 1) ? w1x : (g == 2) ? w2x : w3x;
    int off = comp * (128 * 256) + p * 256 + q;
    unsigned short v;
    if (fl) { v = ((const unsigned short*)W)[off]; if (neg) v ^= 0x8000u; }
    else    { float f = ((const float*)W)[off]; if (neg) f = -f; v = f2b(f); }
    WXT[i] = v;
    return;
  }
  idx -= PREP_N1;
  if (idx < PREP_N2) {
    int i = (int)idx;
    int n = i >> 10, k = i & 1023;
    int j = n >> 2, g = n & 3;
    int rb = k >> 8, p = k & 255;               // HDIM/4 = 256
    int cb = j >> 8, q = j & 255;
    int comp = rb ^ cb;
    int neg = (rb & 1) && !(cb & 1);
    const void* W = (g == 0) ? w0h : (g == 1) ? w1h : (g == 2) ? w2h : w3h;
    int off = comp * (256 * 256) + p * 256 + q;
    unsigned short v;
    if (fl) { v = ((const unsigned short*)W)[off]; if (neg) v ^= 0x8000u; }
    else    { float f = ((const float*)W)[off]; if (neg) f = -f; v = f2b(f); }
    WHT[i] = v;
    return;
  }
  idx -= PREP_N2;
  if (idx < PREP_N3) {
    int i = (int)idx;                           // < 4096
    int j = i >> 2, g = i & 3;
    const void* B = (g == 0) ? b0 : (g == 1) ? b1 : (g == 2) ? b2 : b3;
    biasI[i] = fl ? b2f(((const unsigned short*)B)[j]) : ((const float*)B)[j];
    return;
  }
  idx -= PREP_N3;
  if (idx < PREP_N4V) {
    uint4 z = {0u, 0u, 0u, 0u};
    *(uint4*)&hring0[(int)idx * 8] = z;         // h[0] = 0
    return;
  }
  idx -= PREP_N4V;
  if (idx < PREP_N5) { flags[(int)idx] = 0; return; }    // barrier flags = 0
  idx -= PREP_N5;
  {
    int i = (int)idx;                           // < NCLS*HDIM
    int col = i >> 10, k = i & 1023;
    float v = fl ? b2f(((const unsigned short*)fcw)[k * NCLS + col])
                 : ((const float*)fcw)[k * NCLS + col];
    fcwT[col * 1024 + k] = v;                   // contiguous write
  }
}

// ---- fast tail dot: 512-length partial dot, fcwT contiguous-k f32 ----
static __device__ __forceinline__ float dot512T(const unsigned short* __restrict__ hfin,
                                                const float* __restrict__ fcwT,
                                                int b, int col, int half) {
  const float* wcol = fcwT + (size_t)col * 1024 + half * 512;
  float s0 = 0.f, s1 = 0.f, s2 = 0.f, s3 = 0.f;
#pragma unroll 4
  for (int c = 0; c < 32; ++c) {
    int k16 = half * 32 + c;                    // 16-element k-chunk
    const unsigned short* hp = hfin + k16 * 256 + b * 16;
    bfv8 h0 = *(const bfv8*)hp;
    bfv8 h1 = *(const bfv8*)(hp + 8);
    const float4* wp = (const float4*)(wcol + c * 16);
    float4 w0 = wp[0], w1 = wp[1], w2 = wp[2], w3 = wp[3];
    s0 = fmaf(b2f((unsigned short)h0[0]), w0.x, s0);
    s1 = fmaf(b2f((unsigned short)h0[1]), w0.y, s1);
    s2 = fmaf(b2f((unsigned short)h0[2]), w0.z, s2);
    s3 = fmaf(b2f((unsigned short)h0[3]), w0.w, s3);
    s0 = fmaf(b2f((unsigned short)h0[4]), w1.x, s0);
    s1 = fmaf(b2f((unsigned short)h0[5]), w1.y, s1);
    s2 = fmaf(b2f((unsigned short)h0[6]), w1.z, s2);
    s3 = fmaf(b2f((unsigned short)h0[7]), w1.w, s3);
    s0 = fmaf(b2f((unsigned short)h1[0]), w2.x, s0);
    s1 = fmaf(b2f((unsigned short)h1[1]), w2.y, s1);
    s2 = fmaf(b2f((unsigned short)h1[2]), w2.z, s2);
    s3 = fmaf(b2f((unsigned short)h1[3]), w2.w, s3);
    s0 = fmaf(b2f((unsigned short)h1[4]), w3.x, s0);
    s1 = fmaf(b2f((unsigned short)h1[5]), w3.y, s1);
    s2 = fmaf(b2f((unsigned short)h1[6]), w3.z, s2);
    s3 = fmaf(b2f((unsigned short)h1[7]), w3.w, s3);
  }
  return (s0 + s1) + (s2 + s3);
}

// ---- Phase B: 128-step recurrence + fused final linear.
// Loop: BYTE-FAITHFUL R12 (measured best). Stride-16 flags (one inter-XCD
// writer per cache line — R15's lesson). wave0: store -> vmcnt(0) -> flag ->
// poll, x-GEMM deferred to next iteration top (under h-load latency);
// waves 1-3: x-GEMM(t+1) -> poll. No barriers in the sync path.
// R17: tail GEMV now reads fcwT (f32, contiguous k) — the R16 tail's
// 2052B-strided fcw walk was ~100us of latency-bound line misses.
__global__ void __launch_bounds__(256, 1) phaseB_k(const unsigned short* __restrict__ xbf,
                                                   const unsigned short* __restrict__ WXT,
                                                   const unsigned short* __restrict__ WHT,
                                                   const float* __restrict__ biasI,
                                                   unsigned short* __restrict__ hring,
                                                   int* __restrict__ flags,
                                                   const int* __restrict__ flagp,
                                                   const float* __restrict__ fcwT,
                                                   const void* __restrict__ fcb,
                                                   void* __restrict__ out) {
  __shared__ unsigned short Wh[64][1032];     // 64 n-cols x 1024 k (+8 pad): 132 KB
  __shared__ float Pl[4][16][16];             // per-wave transpose staging
  __shared__ __align__(16) unsigned short Hp[16][16];  // block h gather
  __shared__ float Cred[128];                 // tail split-K combine
  int tid = threadIdx.x;
  int fl = *flagp;
  int grp = blockIdx.x >> 6;                  // 0..3 : batch group
  int blk = blockIdx.x & 63;                  // 0..63: N-col block within group
  int n0  = blk * 64;
  for (int c = tid; c < 64 * 128; c += 256) {
    int row = c >> 7, ch = c & 127;
    *(uint4*)&Wh[row][ch * 8] = *(const uint4*)&WHT[(size_t)(n0 + row) * HDIM + ch * 8];
  }
  __syncthreads();
  int w = tid >> 6, lane = tid & 63;
  int col = lane & 15, quad = lane >> 4;
  int gbatch = grp * 16 + col;                // A-frag batch row AND elementwise batch
  const unsigned short* whp = &Wh[w * 16 + col][quad * 8];
  const unsigned short* wxp = WXT + (size_t)(n0 + w * 16 + col) * FDIM + quad * 8;
  float4 bv = *(const float4*)&biasI[n0 + w * 16 + quad * 4];  // lane's unit gate biases
  int* myflag   = flags + (grp * 64 + blk) * 16;   // this block's flag (64 B stride)
  int* pollflag = flags + (grp * 64 + lane) * 16;  // lane-parallel poll target
  // Consumer fragment base (block-major slot layout). Lane (col,quad),
  // fragment f needs units [f*32+quad*8, +8) of batch gbatch:
  //   blk' = 2f + (quad>>1), u16 = (quad&1)*8  ->  element offset f*512 + fbase.
  size_t fbase = (size_t)grp * 16384 + (size_t)(quad >> 1) * 256
               + (size_t)col * 16 + (size_t)(quad & 1) * 8;
  // Producer region: this block's contiguous 256 elements (512B).
  size_t pregion = (size_t)grp * 16384 + (size_t)blk * 256;
  float creg = 0.0f;                          // c state thread-private
  // prologue: gx for t=0 (all waves)
  fv4 gx0 = {0.f, 0.f, 0.f, 0.f}, gx1 = {0.f, 0.f, 0.f, 0.f};
  {
    const unsigned short* xrow = xbf + (size_t)gbatch * FDIM + quad * 8;
#pragma unroll
    for (int k0 = 0; k0 < FDIM; k0 += 64) {
      bfv8 a0 = *(const bfv8*)(xrow + k0);
      bfv8 b0 = *(const bfv8*)(wxp + k0);
      bfv8 a1 = *(const bfv8*)(xrow + k0 + 32);
      bfv8 b1 = *(const bfv8*)(wxp + k0 + 32);
      gx0 = __builtin_amdgcn_mfma_f32_16x16x32_bf16(a0, b0, gx0, 0, 0, 0);
      gx1 = __builtin_amdgcn_mfma_f32_16x16x32_bf16(a1, b1, gx1, 0, 0, 0);
    }
  }
  for (int t = 0; t < T_STEPS; ++t) {
    const unsigned short* hin  = hring + (size_t)t * HSLOT;
    unsigned short*       hout = hring + (size_t)(t + 1) * HSLOT;
    // h A-fragments, plain cached 16B loads (ring slot lines are fresh ->
    // never stale; dispatch-boundary acquire invalidates across reps).
    const uint4* hq = (const uint4*)(hin + fbase);
    uint4 hs[32];
#pragma unroll
    for (int f = 0; f < 32; ++f) hs[f] = hq[f * 64];   // stride 512 elem = 1KB
    if (w == 0 && t > 0) {
      // Wave0's x-GEMM for CURRENT t, deferred from iteration t-1 so the
      // flag could fire early. Executes under the h-load latency above.
      fv4 g0 = {0.f, 0.f, 0.f, 0.f}, g1 = {0.f, 0.f, 0.f, 0.f};
      const unsigned short* xrow = xbf + (size_t)(t * BATCH + gbatch) * FDIM + quad * 8;
#pragma unroll
      for (int k0 = 0; k0 < FDIM; k0 += 64) {
        bfv8 a0v = *(const bfv8*)(xrow + k0);
        bfv8 b0v = *(const bfv8*)(wxp + k0);
        bfv8 a1v = *(const bfv8*)(xrow + k0 + 32);
        bfv8 b1v = *(const bfv8*)(wxp + k0 + 32);
        g0 = __builtin_amdgcn_mfma_f32_16x16x32_bf16(a0v, b0v, g0, 0, 0, 0);
        g1 = __builtin_amdgcn_mfma_f32_16x16x32_bf16(a1v, b1v, g1, 0, 0, 0);
      }
      gx0 = g0; gx1 = g1;
    }
    fv4 acc0 = gx0, acc1 = gx1;               // start from x-GEMM result
#pragma unroll
    for (int f = 0; f < 32; f += 2) {
      union { uint4 q; bfv8 v; } ua, ub;
      ua.q = hs[f];
      ub.q = hs[f + 1];
      bfv8 b0 = *(const bfv8*)(whp + f * 32);
      bfv8 b1 = *(const bfv8*)(whp + (f + 1) * 32);
      acc0 = __builtin_amdgcn_mfma_f32_16x16x32_bf16(ua.v, b0, acc0, 0, 0, 0);
      acc1 = __builtin_amdgcn_mfma_f32_16x16x32_bf16(ub.v, b1, acc1, 0, 0, 0);
    }
    fv4 acc = acc0 + acc1;
    // Wave-local transpose through LDS (writer wave == reader wave; no barrier).
#pragma unroll
    for (int r = 0; r < 4; ++r) Pl[w][quad * 4 + r][col] = acc[r];  // D: m=quad*4+r, n=col
    asm volatile("" ::: "memory");
    __builtin_amdgcn_s_waitcnt(0);            // ds_writes visible to own wave's ds_read
    asm volatile("" ::: "memory");
    float4 pv = *(const float4*)&Pl[w][col][quad * 4];  // (batch=col, 4 gates of unit quad)
    float fg = sigm(pv.x + bv.x);
    float ig = sigm(pv.y + bv.y);
    float og = sigm(pv.z + bv.z);
    float av = pv.w + bv.w;
    float cn = ig * tanh_f(av) + fg * creg;
    float hn = og * tanh_f(cn);
    creg = cn;
    // Gather the block's 16 batch x 16 units into LDS (batch-major, 2B each).
    Hp[col][w * 4 + quad] = f2b(hn);
    __syncthreads();                          // (A) Hp complete
    // Wave0: single coalesced store of the whole 512B region (8 full lines),
    // then ack + flag IMMEDIATELY (earliest legal point).
    if (w == 0) {
      u64 pk = ((const u64*)&Hp[0][0])[lane];
      __hip_atomic_store((u64*)(hout + pregion) + lane, pk,
                         __ATOMIC_RELAXED, __HIP_MEMORY_SCOPE_AGENT);
    }
    if (t + 1 < T_STEPS) {
      if (w == 0) {
        asm volatile("s_waitcnt vmcnt(0)" ::: "memory");   // h stores at IF$
        if (lane == 0)
          __hip_atomic_store(myflag, t + 1, __ATOMIC_RELAXED, __HIP_MEMORY_SCOPE_AGENT);
      } else {
        // Waves 1-3: x-GEMM for t+1 overlaps the flag-propagation window.
        fv4 g0 = {0.f, 0.f, 0.f, 0.f}, g1 = {0.f, 0.f, 0.f, 0.f};
        const unsigned short* xrow = xbf + (size_t)((t + 1) * BATCH + gbatch) * FDIM + quad * 8;
#pragma unroll
        for (int k0 = 0; k0 < FDIM; k0 += 64) {
          bfv8 a0v = *(const bfv8*)(xrow + k0);
          bfv8 b0v = *(const bfv8*)(wxp + k0);
          bfv8 a1v = *(const bfv8*)(xrow + k0 + 32);
          bfv8 b1v = *(const bfv8*)(wxp + k0 + 32);
          g0 = __builtin_amdgcn_mfma_f32_16x16x32_bf16(a0v, b0v, g0, 0, 0, 0);
          g1 = __builtin_amdgcn_mfma_f32_16x16x32_bf16(a1v, b1v, g1, 0, 0, 0);
        }
        gx0 = g0; gx1 = g1;
      }
      asm volatile("" ::: "memory");
      // ALL waves poll independently (per-lane early-out); no release barrier.
      u64 done = 0;
      for (;;) {
        int v = 0;
        if (!((done >> lane) & 1))
          v = __hip_atomic_load(pollflag, __ATOMIC_RELAXED, __HIP_MEMORY_SCOPE_AGENT);
        done |= __ballot(v >= t + 1);
        if (done == ~0ull) break;
        __builtin_amdgcn_s_sleep(1);
      }
      asm volatile("" ::: "memory");
    }
  }
  // ---- Appended final sync round (t=128): make final h agent-visible ----
  if (w == 0) {
    asm volatile("s_waitcnt vmcnt(0)" ::: "memory");       // t=127 h stores acked
    if (lane == 0)
      __hip_atomic_store(myflag, T_STEPS, __ATOMIC_RELAXED, __HIP_MEMORY_SCOPE_AGENT);
  }
  {
    u64 done = 0;
    for (;;) {
      int v = 0;
      if (!((done >> lane) & 1))
        v = __hip_atomic_load(pollflag, __ATOMIC_RELAXED, __HIP_MEMORY_SCOPE_AGENT);
      done |= __ballot(v >= T_STEPS);
      if (done == ~0ull) break;
      __builtin_amdgcn_s_sleep(1);
    }
  }
  asm volatile("" ::: "memory");
  // ---- Fused final linear: out = h @ fco_W + fco_b (fcwT fast path) ----
  {
    const unsigned short* hfin = hring + (size_t)T_STEPS * HSLOT + (size_t)grp * 16384;
    int b    = tid & 15;          // batch within group
    int cc   = (tid >> 4) & 7;    // col offset within block's 8-col slice
    int half = tid >> 7;          // K half (0: k<512, 1: k>=512)
    int colm = blk * 8 + cc;      // cols 0..511
    float s = dot512T(hfin, fcwT, b, colm, half);
    if (half) Cred[tid & 127] = s;
    __syncthreads();
    if (!half) {
      float r = s + Cred[tid];
      float bias = fl ? b2f(((const unsigned short*)fcb)[colm])
                      : ((const float*)fcb)[colm];
      r += bias;
      int oidx = (grp * 16 + b) * NCLS + colm;
      if (fl) ((unsigned short*)out)[oidx] = f2b(r);
      else    ((float*)out)[oidx] = r;
    }
    if (blk == 63) {              // the 513th class column
      float s2 = 0.f;
      if (tid < 32) s2 = dot512T(hfin, fcwT, tid & 15, 512, tid >> 4);
      __syncthreads();
      if (tid < 32 && (tid >> 4)) Cred[tid & 15] = s2;
      __syncthreads();
      if (tid < 16) {
        float r = s2 + Cred[tid];
        r += fl ? b2f(((const unsigned short*)fcb)[512]) : ((const float*)fcb)[512];
        int oidx = (grp * 16 + tid) * NCLS + 512;
        if (fl) ((unsigned short*)out)[oidx] = f2b(r);
        else    ((float*)out)[oidx] = r;
      }
    }
  }
}

extern "C" void kernel_launch(void* const* d_in, const int* in_sizes, int n_in,
                              void* d_out, int out_size, void* d_ws, size_t ws_size,
                              hipStream_t stream) {
  const void* x   = d_in[0];
  const void* wfx = d_in[1];  const void* bfv = d_in[2];  const void* wfh = d_in[3];
  const void* wix = d_in[4];  const void* biv = d_in[5];  const void* wih = d_in[6];
  const void* wox = d_in[7];  const void* bov = d_in[8];  const void* woh = d_in[9];
  const void* wcx = d_in[10]; const void* bcv = d_in[11]; const void* wch = d_in[12];
  const void* fcw = d_in[13]; const void* fcb = d_in[14];

  char* ws = (char*)d_ws;
  int*            flag  = (int*)           (ws);                 // 256 B
  unsigned short* WXT   = (unsigned short*)(ws + 256);           // 4 MB
  unsigned short* WHT   = (unsigned short*)(ws + 4194560);       // 8 MB
  float*          biasI = (float*)         (ws + 12583168);      // 16 KB
  unsigned short* xbf   = (unsigned short*)(ws + 12599552);      // 8 MB
  unsigned short* hring = (unsigned short*)(ws + 20988160);      // 129 x 128 KB = 16.9 MB
  int*            flags = (int*)           (ws + 37896448);      // 16 KB
  float*          fcwT  = (float*)         (ws + 37912832);      // 2.1 MB -> total ~40 MB

  detect_k<<<1, 256, 0, stream>>>((const unsigned short*)x, flag);
  prep_k<<<PREP_TOTAL / 256, 256, 0, stream>>>(x, wfx, wix, wox, wcx,
                                               wfh, wih, woh, wch,
                                               bfv, biv, bov, bcv, fcw,
                                               flag, xbf, WXT, WHT, biasI,
                                               hring, flags, fcwT);

  const unsigned short* p_x = xbf;
  const unsigned short* p_wx = WXT;
  const unsigned short* p_wh = WHT;
  const float* p_bi = biasI;
  unsigned short* p_hr = hring;
  int* p_fl = flags;
  const int* p_flag = flag;
  const float* p_fcwT = fcwT;
  const void* p_fcb = fcb;
  void* p_out = d_out;
  void* kargs[] = { (void*)&p_x, (void*)&p_wx, (void*)&p_wh, (void*)&p_bi,
                    (void*)&p_hr, (void*)&p_fl, (void*)&p_flag,
                    (void*)&p_fcwT, (void*)&p_fcb, (void*)&p_out };
  hipLaunchCooperativeKernel((void*)phaseB_k, dim3(256), dim3(256), kargs, 0, stream);
}